// Round 1
// baseline (555.533 us; speedup 1.0000x reference)
//
#include <hip/hip_runtime.h>
#include <hip/hip_bf16.h>
#include <cstddef>

// Problem constants (match reference).
#define NQ 8192
#define DD 1024

typedef __attribute__((ext_vector_type(8))) short s8v;     // 8 bf16 (4 VGPR)
typedef __attribute__((ext_vector_type(8))) int i8v;       // 32 fp8 bytes (8 VGPR)
typedef __attribute__((ext_vector_type(4))) float f32x4;   // 16x16 C/D frag
typedef __attribute__((ext_vector_type(16))) float f32x16; // 32x32 C/D frag

typedef const __attribute__((address_space(1))) unsigned int* gptr_t;
typedef __attribute__((address_space(3))) unsigned int* lptr_t;

#define SCALE_1_16 0x7B7B7B7Bu  // E8M0 123 = 2^-4 in every byte

__device__ inline unsigned short f2bf(float f) {
  union { float f; unsigned u; } v; v.f = f;
  unsigned r = (v.u + 0x7FFFu + ((v.u >> 16) & 1u)) >> 16;  // RNE
  return (unsigned short)r;
}
__device__ inline float bf2f(unsigned short u) {
  union { unsigned u; float f; } v; v.u = ((unsigned)u) << 16;
  return v.f;
}
__device__ inline float bits2f(unsigned u) {
  union { unsigned u; float f; } v; v.u = u;
  return v.f;
}

// f32 -> OCP e4m3 bits, RNE, clamp to +-448.
__device__ inline unsigned char f2e4m3(float x) {
  union { float f; unsigned u; } v; v.f = x;
  const unsigned s = (v.u >> 31) << 7;
  unsigned au = v.u & 0x7FFFFFFFu;
  if (au > 0x43E00000u) au = 0x43E00000u;  // clamp |x| to 448.0
  if (au >= 0x3C800000u) {                 // |x| >= 2^-6: e4m3 normal
    const unsigned rounded = au + 0x7FFFFu + ((au >> 20) & 1u);  // RNE @ 3 mant
    const unsigned e8 = ((rounded >> 23) & 0xFF) - 120u;         // -127+7
    const unsigned m8 = (rounded >> 20) & 7u;
    return (unsigned char)(s | (e8 << 3) | m8);
  } else {                                 // subnormal
    union { unsigned u; float f; } a; a.u = au;
    const unsigned q = (unsigned)rintf(a.f * 512.0f);  // 0..8
    return (unsigned char)(s | q);
  }
}

// Register-only combine of two 16-B LDS loads into one fp8 MFMA operand.
__device__ inline i8v make_i8v(int4 a, int4 b) {
  i8v v;
  v[0] = a.x; v[1] = a.y; v[2] = a.z; v[3] = a.w;
  v[4] = b.x; v[5] = b.y; v[6] = b.z; v[7] = b.w;
  return v;
}

// ---------------------------------------------------------------------------
// m97-style bf16 MFMA main loop: C(128x128) += A(128xK) @ B(128xK)^T.
// BK=64, global_load_lds dwordx4 staging, 4 waves, each 64x64 via 4x4 of
// 16x16x32 bf16 MFMA. Used by proj_gemm.
//
// LDS rows are 64 shorts = 128 B = exactly 32 banks, 16-B chunks
// XOR-swizzled by row&7 (global source column permuted; LDS dest linear per
// global_load_lds wave-uniform-base rule). Frag reads: chunk = (4s+lq)^(l16&7).
// ---------------------------------------------------------------------------
template <int KDIM, int ASTR, int BSTR>
__device__ inline void mfma_core(const unsigned short* __restrict__ A,
                                 const unsigned short* __restrict__ B,
                                 int i0, int j0, int tid,
                                 unsigned short* AsU, unsigned short* BsU,
                                 f32x4 (&acc)[4][4]) {
  const int lane = tid & 63;
  const int w = tid >> 6;
  const int wr = (w >> 1) * 64;
  const int wc = (w & 1) * 64;
  const int l16 = lane & 15;
  const int lq = lane >> 4;
  const int srow = lane >> 3;                          // 0..7
  const int scol = (((lane & 7) ^ (srow & 7)) * 8);    // swizzled 16-B chunk

  for (int kk = 0; kk < KDIM; kk += 64) {
    __syncthreads();
#pragma unroll
    for (int t = 0; t < 4; t++) {
      const int r0 = w * 32 + t * 8;
      const unsigned short* g = &A[(size_t)(i0 + r0 + srow) * ASTR + kk + scol];
      __builtin_amdgcn_global_load_lds((gptr_t)(const void*)g,
                                       (lptr_t)(void*)&AsU[r0 * 64], 16, 0, 0);
    }
#pragma unroll
    for (int t = 0; t < 4; t++) {
      const int r0 = w * 32 + t * 8;
      const unsigned short* g = &B[(size_t)(j0 + r0 + srow) * BSTR + kk + scol];
      __builtin_amdgcn_global_load_lds((gptr_t)(const void*)g,
                                       (lptr_t)(void*)&BsU[r0 * 64], 16, 0, 0);
    }
    __syncthreads();

    const int h = l16 & 7;
    s8v af[4][2], bf[4][2];
#pragma unroll
    for (int t = 0; t < 4; t++)
#pragma unroll
      for (int s = 0; s < 2; s++) {
        const int ch = ((s * 4 + lq) ^ h) * 8;  // swizzled chunk offset
        af[t][s] = *(const s8v*)&AsU[(wr + 16 * t + l16) * 64 + ch];
        bf[t][s] = *(const s8v*)&BsU[(wc + 16 * t + l16) * 64 + ch];
      }
#pragma unroll
    for (int s = 0; s < 2; s++)
#pragma unroll
      for (int a = 0; a < 4; a++)
#pragma unroll
        for (int b = 0; b < 4; b++)
          acc[a][b] = __builtin_amdgcn_mfma_f32_16x16x32_bf16(
              af[a][s], bf[b][s], acc[a][b], 0, 0, 0);
  }
}

// ---------------------------------------------------------------------------
// fp32 -> bf16 elementwise.
// ---------------------------------------------------------------------------
__global__ void f32_to_bf16(const float* __restrict__ in,
                            unsigned short* __restrict__ out, int n4) {
  int i = (blockIdx.x * blockDim.x + threadIdx.x);
  if (i < n4) {
    const float4 v = *(const float4*)&in[i * 4];
    ushort4 o;
    o.x = f2bf(v.x); o.y = f2bf(v.y); o.z = f2bf(v.z); o.w = f2bf(v.w);
    *(ushort4*)&out[i * 4] = o;
  }
}

__global__ void zero_f32(float* __restrict__ p, int n) {
  const int i = blockIdx.x * blockDim.x + threadIdx.x;
  if (i < n) p[i] = 0.f;
}

// ---------------------------------------------------------------------------
// fp32 [R][C] -> bf16 [C][R] transpose+convert (32x32 LDS tiles).
// ---------------------------------------------------------------------------
__global__ void transpose_cvt(const float* __restrict__ in,
                              unsigned short* __restrict__ out, int R, int C) {
  __shared__ float t[32][33];
  const int bx = blockIdx.x;
  const int by = blockIdx.y;
  const int x = threadIdx.x & 31;
  const int y = threadIdx.x >> 5;
#pragma unroll
  for (int i = 0; i < 32; i += 8)
    t[y + i][x] = in[(size_t)(by * 32 + y + i) * C + bx * 32 + x];
  __syncthreads();
#pragma unroll
  for (int i = 0; i < 32; i += 8)
    out[(size_t)(bx * 32 + y + i) * R + by * 32 + x] = f2bf(t[x][y + i]);
}

// ---------------------------------------------------------------------------
// Projection GEMM: C[m][n] = sum_k A[m][k] * BT[n][k], bf16 in, K=1024.
// FP8OUT=true writes e4m3(16*value) for the MX qk pass.
// ---------------------------------------------------------------------------
template <int NST, bool FP8OUT>
__global__ __launch_bounds__(256, 2)
void proj_gemm(const unsigned short* __restrict__ A,
               const unsigned short* __restrict__ BT,
               void* __restrict__ Cout) {
  __shared__ __align__(16) unsigned short As[128 * 64];
  __shared__ __align__(16) unsigned short Bs[128 * 64];
  const int tid = threadIdx.x;
  const int m0 = blockIdx.y * 128;
  const int n0 = blockIdx.x * 128;

  f32x4 acc[4][4];
#pragma unroll
  for (int a = 0; a < 4; a++)
#pragma unroll
    for (int b = 0; b < 4; b++) acc[a][b] = (f32x4){0.f, 0.f, 0.f, 0.f};

  mfma_core<DD, DD, DD>(A, BT, m0, n0, tid, As, Bs, acc);

  const int lane = tid & 63;
  const int w = tid >> 6;
  const int wr = (w >> 1) * 64, wc = (w & 1) * 64;
  const int l16 = lane & 15, lq = lane >> 4;
#pragma unroll
  for (int ti = 0; ti < 4; ti++)
#pragma unroll
    for (int r = 0; r < 4; r++) {
      const int row = m0 + wr + 16 * ti + lq * 4 + r;
#pragma unroll
      for (int tj = 0; tj < 4; tj++) {
        const int col = n0 + wc + 16 * tj + l16;
        if (FP8OUT) {
          ((unsigned char*)Cout)[(size_t)row * NST + col] =
              f2e4m3(acc[ti][tj][r] * 16.f);
        } else {
          ((unsigned short*)Cout)[(size_t)row * NST + col] = f2bf(acc[ti][tj][r]);
        }
      }
    }
}

// ---------------------------------------------------------------------------
// Pass 1: P = exp(xi @ xi^T) via MX-scaled fp8 MFMA (2x bf16 rate).
// xif holds e4m3(16*xi); both MFMA scales = 2^-4 undo the pre-scaling.
// 128x128 tile, 4 waves, each 64x64 = 2x2 of mfma_scale_f32_32x32x64_f8f6f4.
// Epilogue now ALSO produces row sums (fused row_sum): per-row reduce over the
// block's 128 cols via __shfl_xor within the 32-lane col group, one
// atomicAdd(&lsum[row]) per row per block.  Saves the 128 MB P re-read.
// ---------------------------------------------------------------------------
__global__ __launch_bounds__(256, 2)
void qk_fp8(const unsigned char* __restrict__ xif,  // [8192][1024] e4m3
            unsigned short* __restrict__ P,         // [8192][8192] bf16 bits
            float* __restrict__ lsum) {             // [8192] fp32 (pre-zeroed)
  __shared__ __align__(16) unsigned char AsF[128 * 64];
  __shared__ __align__(16) unsigned char BsF[128 * 64];
  const int tid = threadIdx.x;
  const int lane = tid & 63;
  const int w = tid >> 6;
  const int i0 = blockIdx.y * 128;
  const int j0 = blockIdx.x * 128;

  f32x16 acc[2][2];
#pragma unroll
  for (int a = 0; a < 2; a++)
#pragma unroll
    for (int b = 0; b < 2; b++)
#pragma unroll
      for (int r = 0; r < 16; r++) acc[a][b][r] = 0.f;

  const int srow = lane >> 2;  // 0..15: row within 16-row staging group
  const int slot = lane & 3;   // 16-B chunk slot within the row
  const int kb = lane >> 5;    // frag k-block (0/1)
  const int l31 = lane & 31;

  for (int kk = 0; kk < DD; kk += 64) {
    __syncthreads();
#pragma unroll
    for (int t = 0; t < 2; t++) {
      const int r = w * 32 + t * 16 + srow;
      const int c = slot ^ ((r >> 1) & 3);  // logical chunk for this slot
      const unsigned char* ga = &xif[(size_t)(i0 + r) * DD + kk + c * 16];
      const unsigned char* gb = &xif[(size_t)(j0 + r) * DD + kk + c * 16];
      __builtin_amdgcn_global_load_lds((gptr_t)(const void*)ga,
                                       (lptr_t)(void*)&AsF[(w * 32 + t * 16) * 64],
                                       16, 0, 0);
      __builtin_amdgcn_global_load_lds((gptr_t)(const void*)gb,
                                       (lptr_t)(void*)&BsF[(w * 32 + t * 16) * 64],
                                       16, 0, 0);
    }
    __syncthreads();

    i8v af[2], bf[2];
#pragma unroll
    for (int mi = 0; mi < 2; mi++) {
      const int ar = (w >> 1) * 64 + mi * 32 + l31;
      const int sw = (ar >> 1) & 3;
      const int4 q0 = *(const int4*)&AsF[ar * 64 + ((2 * kb + 0) ^ sw) * 16];
      const int4 q1 = *(const int4*)&AsF[ar * 64 + ((2 * kb + 1) ^ sw) * 16];
      af[mi] = make_i8v(q0, q1);
    }
#pragma unroll
    for (int nj = 0; nj < 2; nj++) {
      const int br = (w & 1) * 64 + nj * 32 + l31;
      const int sw = (br >> 1) & 3;
      const int4 q0 = *(const int4*)&BsF[br * 64 + ((2 * kb + 0) ^ sw) * 16];
      const int4 q1 = *(const int4*)&BsF[br * 64 + ((2 * kb + 1) ^ sw) * 16];
      bf[nj] = make_i8v(q0, q1);
    }
#pragma unroll
    for (int mi = 0; mi < 2; mi++)
#pragma unroll
      for (int nj = 0; nj < 2; nj++)
        acc[mi][nj] = __builtin_amdgcn_mfma_scale_f32_32x32x64_f8f6f4(
            af[mi], bf[nj], acc[mi][nj], 0 /*cbsz: fp8*/, 0 /*blgp: fp8*/,
            0, SCALE_1_16, 0, SCALE_1_16);
  }

  // Epilogue: p = exp(s) -> P (bf16) + fused partial row sums -> lsum.
  // 32x32 C layout: row = (reg&3) + 8*(reg>>2) + 4*(lane>>5), col = lane&31.
  const int mbase = (w >> 1) * 64;
  const int nbase = (w & 1) * 64;
  const int rowoff = 4 * (lane >> 5);
#pragma unroll
  for (int mi = 0; mi < 2; mi++) {
    float p0[16], p1[16], rs[16];
#pragma unroll
    for (int reg = 0; reg < 16; reg++) {
      p0[reg] = __expf(acc[mi][0][reg]);
      p1[reg] = __expf(acc[mi][1][reg]);
      rs[reg] = p0[reg] + p1[reg];
    }
    // Reduce across the 32-lane column group (rows identical within group).
#pragma unroll
    for (int m = 1; m <= 16; m <<= 1)
#pragma unroll
      for (int reg = 0; reg < 16; reg++) rs[reg] += __shfl_xor(rs[reg], m);
    if (l31 == 0) {
#pragma unroll
      for (int reg = 0; reg < 16; reg++) {
        const int rl = mbase + mi * 32 + (reg & 3) + 8 * (reg >> 2) + rowoff;
        atomicAdd(&lsum[i0 + rl], rs[reg]);
      }
    }
#pragma unroll
    for (int reg = 0; reg < 16; reg++) {
      const int rl = mbase + mi * 32 + (reg & 3) + 8 * (reg >> 2) + rowoff;
      const size_t base = (size_t)(i0 + rl) * NQ + j0 + nbase + l31;
      P[base]      = f2bf(p0[reg]);
      P[base + 32] = f2bf(p1[reg]);
    }
  }
}

// ---------------------------------------------------------------------------
// Pass 2 (pv8): out = (P @ supT^T) / lsum[row], K = 8192 (bf16).
// 8-phase counted-vmcnt pipeline (T2+T3+T4+T5), tile 256x128, BK=64, 8 waves
// (4m x 2n), wave-tile 64x64, acc[4][4] of 16x16x32 bf16 MFMA.
// LDS = double-buffered A(256x64) + B(128x64) bf16 = 96 KB -> 1 block/CU;
// grid 32x8 = 256 blocks = exactly one per CU.
//
// Per iter = 2 K-tiles = 8 phases. Phase p reads A m-frag pair m=p (+ all
// B-frags at p==0), issues global_load_lds prefetch for K-tiles t+2/t+3 into
// regions freed by the PREVIOUS phase, then: barrier; MFMA (setprio 1);
// counted s_waitcnt vmcnt(N); barrier.  vmcnt is never drained to 0 in the
// main loop; every prefetch has 6-7 phases of flight time.
//
// Region free/read schedule (A band = 32 rows staged by one wave; even bands
// read phases 0-1, odd bands phases 2-3 of their tile's half; B read at
// phase 0 only -> B-frags held in registers across the 4 phases):
//   even waves stage: P1 B(t+2), P2 A(t+2), P5 B(t+3), P6 A(t+3)
//   odd  waves stage: P0 A(t+1), P1 B(t+2), P4 A(t+2), P5 B(t+3)
// Exact per-class vmcnt constants (derived from issue order; see analysis):
//   even: B0=6  B3=8  B4=6  B7=8      odd: B1=10 B2=8 B3=6 B5=10 B6=8 B7=6
// Last iter peeled with vmcnt(0) everywhere (steady constants under-wait when
// the guard skips the out-of-range stages).
// ---------------------------------------------------------------------------
__device__ __forceinline__ s8v rd_frag(const unsigned short* S, int row, int s,
                                       int lq, int l16) {
  return *(const s8v*)&S[row * 64 + (((s * 4 + lq) ^ (l16 & 7)) * 8)];
}

__device__ __forceinline__ void pv_bar() {
  asm volatile("" ::: "memory");
  __builtin_amdgcn_s_barrier();
  asm volatile("" ::: "memory");
}

__device__ __forceinline__ void pv_stage_A(const unsigned short* __restrict__ Ag,
                                           int i0, int w, int srow, int scol,
                                           int T, unsigned short* dst) {
#pragma unroll
  for (int t = 0; t < 4; t++) {
    const unsigned short* g =
        &Ag[(size_t)(i0 + w * 32 + t * 8 + srow) * NQ + T * 64 + scol];
    __builtin_amdgcn_global_load_lds((gptr_t)(const void*)g,
                                     (lptr_t)(void*)&dst[(w * 32 + t * 8) * 64],
                                     16, 0, 0);
  }
}

__device__ __forceinline__ void pv_stage_B(const unsigned short* __restrict__ Bg,
                                           int n0, int w, int srow, int scol,
                                           int T, unsigned short* dst) {
#pragma unroll
  for (int t = 0; t < 2; t++) {
    const unsigned short* g =
        &Bg[(size_t)(n0 + w * 16 + t * 8 + srow) * NQ + T * 64 + scol];
    __builtin_amdgcn_global_load_lds((gptr_t)(const void*)g,
                                     (lptr_t)(void*)&dst[(w * 16 + t * 8) * 64],
                                     16, 0, 0);
  }
}

#define PV_VM(N) asm volatile("s_waitcnt vmcnt(" #N ")" ::: "memory")

#define PV_LOADB(BS)                                                \
  _Pragma("unroll") for (int n = 0; n < 4; n++) {                   \
    bf[n][0] = rd_frag(BS, wn * 64 + n * 16 + l16, 0, lq, l16);     \
    bf[n][1] = rd_frag(BS, wn * 64 + n * 16 + l16, 1, lq, l16);     \
  }

#define PV_PHASE(M, AS, LOADB, STAGE, VMW)                                   \
  {                                                                          \
    const int arow_ = wm * 64 + (M) * 16 + l16;                              \
    const s8v a0_ = rd_frag(AS, arow_, 0, lq, l16);                          \
    const s8v a1_ = rd_frag(AS, arow_, 1, lq, l16);                          \
    LOADB                                                                    \
    STAGE                                                                    \
    pv_bar();                                                                \
    __builtin_amdgcn_s_setprio(1);                                          \
    _Pragma("unroll") for (int n = 0; n < 4; n++)                            \
        acc[M][n] = __builtin_amdgcn_mfma_f32_16x16x32_bf16(                 \
            a0_, bf[n][0], acc[M][n], 0, 0, 0);                              \
    _Pragma("unroll") for (int n = 0; n < 4; n++)                            \
        acc[M][n] = __builtin_amdgcn_mfma_f32_16x16x32_bf16(                 \
            a1_, bf[n][1], acc[M][n], 0, 0, 0);                              \
    __builtin_amdgcn_s_setprio(0);                                          \
    VMW                                                                      \
    pv_bar();                                                                \
  }

template <bool ODD, bool LAST>
__device__ __forceinline__ void pv_iter(const unsigned short* __restrict__ P,
                                        const unsigned short* __restrict__ supT,
                                        int i0, int n0, int w, int wm, int wn,
                                        int l16, int lq, int srow, int scol,
                                        int t0, unsigned short* As0,
                                        unsigned short* As1,
                                        unsigned short* Bs0,
                                        unsigned short* Bs1,
                                        f32x4 (&acc)[4][4]) {
  s8v bf[4][2];
  // ---- K-tile t0 (buffers *0) ----
  PV_PHASE(0, As0, PV_LOADB(Bs0),
           { if constexpr (ODD) pv_stage_A(P, i0, w, srow, scol, t0 + 1, As1); },
           { if constexpr (LAST) { PV_VM(0); } else if constexpr (!ODD) { PV_VM(6); } })
  PV_PHASE(1, As0, ,
           { if constexpr (!LAST) pv_stage_B(supT, n0, w, srow, scol, t0 + 2, Bs0); },
           { if constexpr (LAST) { PV_VM(0); } else if constexpr (ODD) { PV_VM(10); } })
  PV_PHASE(2, As0, ,
           { if constexpr (!ODD && !LAST) pv_stage_A(P, i0, w, srow, scol, t0 + 2, As0); },
           { if constexpr (LAST) { PV_VM(0); } else if constexpr (ODD) { PV_VM(8); } })
  PV_PHASE(3, As0, , ,
           { if constexpr (LAST) { PV_VM(0); } else if constexpr (ODD) { PV_VM(6); } else { PV_VM(8); } })
  // ---- K-tile t0+1 (buffers *1) ----
  PV_PHASE(0, As1, PV_LOADB(Bs1),
           { if constexpr (ODD && !LAST) pv_stage_A(P, i0, w, srow, scol, t0 + 2, As0); },
           { if constexpr (LAST) { PV_VM(0); } else if constexpr (!ODD) { PV_VM(6); } })
  PV_PHASE(1, As1, ,
           { if constexpr (!LAST) pv_stage_B(supT, n0, w, srow, scol, t0 + 3, Bs1); },
           { if constexpr (LAST) { PV_VM(0); } else if constexpr (ODD) { PV_VM(10); } })
  PV_PHASE(2, As1, ,
           { if constexpr (!ODD && !LAST) pv_stage_A(P, i0, w, srow, scol, t0 + 3, As1); },
           { if constexpr (LAST) { PV_VM(0); } else if constexpr (ODD) { PV_VM(8); } })
  PV_PHASE(3, As1, , ,
           { if constexpr (LAST) { PV_VM(0); } else if constexpr (ODD) { PV_VM(6); } else { PV_VM(8); } })
}

__global__ __launch_bounds__(512, 2)
void pv8(const unsigned short* __restrict__ P,
         const unsigned short* __restrict__ supT,
         const float* __restrict__ lsum, float* __restrict__ out) {
  __shared__ __align__(16) unsigned short As[2][256 * 64];  // 64 KB
  __shared__ __align__(16) unsigned short Bs[2][128 * 64];  // 32 KB
  const int tid = threadIdx.x;
  const int lane = tid & 63;
  const int w = tid >> 6;          // 0..7
  const int wm = w >> 1;           // 0..3: 64-row band of the 256-row tile
  const int wn = w & 1;            // 0..1: 64-col band of the 128-col tile
  const int l16 = lane & 15;
  const int lq = lane >> 4;
  const int srow = lane >> 3;                       // staging row 0..7
  const int scol = ((lane & 7) ^ srow) * 8;         // swizzled 16-B chunk
  const int i0 = blockIdx.x * 256;
  const int n0 = blockIdx.y * 128;

  f32x4 acc[4][4];
#pragma unroll
  for (int a = 0; a < 4; a++)
#pragma unroll
    for (int b = 0; b < 4; b++) acc[a][b] = (f32x4){0.f, 0.f, 0.f, 0.f};

  // Prologue: tile0 full; tile1 B (all waves) + A (even waves; odd waves
  // stage their tile1 A bands at P0 of iter 0, matching steady state).
  pv_stage_A(P, i0, w, srow, scol, 0, As[0]);
  pv_stage_B(supT, n0, w, srow, scol, 0, Bs[0]);
  pv_stage_B(supT, n0, w, srow, scol, 1, Bs[1]);
  if (!(w & 1)) pv_stage_A(P, i0, w, srow, scol, 1, As[1]);
  asm volatile("s_waitcnt vmcnt(0)" ::: "memory");
  pv_bar();

  if (w & 1) {
#pragma unroll 1
    for (int i = 0; i < 63; i++)
      pv_iter<true, false>(P, supT, i0, n0, w, wm, wn, l16, lq, srow, scol,
                           2 * i, As[0], As[1], Bs[0], Bs[1], acc);
    pv_iter<true, true>(P, supT, i0, n0, w, wm, wn, l16, lq, srow, scol, 126,
                        As[0], As[1], Bs[0], Bs[1], acc);
  } else {
#pragma unroll 1
    for (int i = 0; i < 63; i++)
      pv_iter<false, false>(P, supT, i0, n0, w, wm, wn, l16, lq, srow, scol,
                            2 * i, As[0], As[1], Bs[0], Bs[1], acc);
    pv_iter<false, true>(P, supT, i0, n0, w, wm, wn, l16, lq, srow, scol, 126,
                         As[0], As[1], Bs[0], Bs[1], acc);
  }

  // Epilogue: divide by row sum, store fp32.
#pragma unroll
  for (int m = 0; m < 4; m++)
#pragma unroll
    for (int r = 0; r < 4; r++) {
      const int row = i0 + wm * 64 + m * 16 + lq * 4 + r;
      const float linv = 1.f / lsum[row];
#pragma unroll
      for (int n = 0; n < 4; n++) {
        const int col = n0 + wn * 64 + n * 16 + l16;
        out[(size_t)row * DD + col] = acc[m][n][r] * linv;
      }
    }
}

// ---------------------------------------------------------------------------
// Fallback fp32 path (round-1) — only if ws_size is too small.
// ---------------------------------------------------------------------------
#define BM 64
#define BN 64
#define BK 16

__global__ __launch_bounds__(256, 4)
void gemm64(const float* __restrict__ A, const float* __restrict__ B,
            float* __restrict__ C, int M, int N, int K) {
  __shared__ __align__(16) float As[BK][BM + 4];
  __shared__ __align__(16) float Bs[BK][BN + 4];
  const int tid = threadIdx.x;
  const int tx = tid & 15;
  const int ty = tid >> 4;
  const int row0 = blockIdx.y * BM;
  const int col0 = blockIdx.x * BN;
  float acc[4][4] = {};
  for (int k0 = 0; k0 < K; k0 += BK) {
    {
      const int r = tid >> 2;
      const int c4 = (tid & 3) * 4;
      const float4 v = *(const float4*)&A[(size_t)(row0 + r) * K + k0 + c4];
      As[c4 + 0][r] = v.x; As[c4 + 1][r] = v.y;
      As[c4 + 2][r] = v.z; As[c4 + 3][r] = v.w;
    }
    {
      const int r = tid >> 4;
      const int c4 = (tid & 15) * 4;
      *(float4*)&Bs[r][c4] = *(const float4*)&B[(size_t)(k0 + r) * N + col0 + c4];
    }
    __syncthreads();
#pragma unroll
    for (int k = 0; k < BK; k++) {
      const float4 a = *(const float4*)&As[k][4 * ty];
      const float4 b = *(const float4*)&Bs[k][4 * tx];
      const float av[4] = {a.x, a.y, a.z, a.w};
      const float bv[4] = {b.x, b.y, b.z, b.w};
#pragma unroll
      for (int i = 0; i < 4; i++)
#pragma unroll
        for (int j = 0; j < 4; j++)
          acc[i][j] += av[i] * bv[j];
    }
    __syncthreads();
  }
#pragma unroll
  for (int i = 0; i < 4; i++) {
    float4 o = {acc[i][0], acc[i][1], acc[i][2], acc[i][3]};
    *(float4*)&C[(size_t)(row0 + 4 * ty + i) * N + col0 + 4 * tx] = o;
  }
}

#define IT 32
#define JT 128
#define KC 32
#define CC 128
#define NCH (DD / CC)

__global__ __launch_bounds__(256, 1)
void fused_attn(const float* __restrict__ xi, const float* __restrict__ sup,
                float* __restrict__ out) {
  __shared__ __align__(16) float XiI[KC][IT + 4];
  __shared__ __align__(16) float XiJ[KC][JT + 4];
  __shared__ __align__(16) float Ps[JT][IT + 4];
  __shared__ __align__(16) float Vs[JT][CC + 4];
  __shared__ float lsum[IT];
  const int tid = threadIdx.x;
  const int i0 = blockIdx.x * IT;
  const int ry = tid >> 5;
  const int cx = tid & 31;
  if (tid < IT) lsum[tid] = 0.f;
  float oacc[NCH][4][4];
#pragma unroll
  for (int ch = 0; ch < NCH; ch++)
#pragma unroll
    for (int i = 0; i < 4; i++)
#pragma unroll
      for (int j = 0; j < 4; j++) oacc[ch][i][j] = 0.f;
  for (int j0 = 0; j0 < NQ; j0 += JT) {
    float sacc[4][4] = {};
    for (int kc = 0; kc < DD; kc += KC) {
      __syncthreads();
      {
        const int r = tid >> 3;
        const int k4 = (tid & 7) * 4;
        const float4 v = *(const float4*)&xi[(size_t)(i0 + r) * DD + kc + k4];
        XiI[k4 + 0][r] = v.x; XiI[k4 + 1][r] = v.y;
        XiI[k4 + 2][r] = v.z; XiI[k4 + 3][r] = v.w;
      }
#pragma unroll
      for (int i = 0; i < 4; i++) {
        const int idx = tid + i * 256;
        const int r = idx >> 3;
        const int k4 = (idx & 7) * 4;
        const float4 v = *(const float4*)&xi[(size_t)(j0 + r) * DD + kc + k4];
        XiJ[k4 + 0][r] = v.x; XiJ[k4 + 1][r] = v.y;
        XiJ[k4 + 2][r] = v.z; XiJ[k4 + 3][r] = v.w;
      }
      __syncthreads();
#pragma unroll
      for (int k = 0; k < KC; k++) {
        const float4 a = *(const float4*)&XiI[k][4 * ry];
        const float4 b = *(const float4*)&XiJ[k][4 * cx];
        const float av[4] = {a.x, a.y, a.z, a.w};
        const float bv[4] = {b.x, b.y, b.z, b.w};
#pragma unroll
        for (int i = 0; i < 4; i++)
#pragma unroll
          for (int j = 0; j < 4; j++)
            sacc[i][j] += av[i] * bv[j];
      }
    }
    __syncthreads();
    float rsv[4] = {0.f, 0.f, 0.f, 0.f};
#pragma unroll
    for (int i = 0; i < 4; i++)
#pragma unroll
      for (int j = 0; j < 4; j++) {
        const float p = __expf(sacc[i][j]);
        Ps[4 * cx + j][4 * ry + i] = p;
        rsv[i] += p;
      }
#pragma unroll
    for (int m = 16; m >= 1; m >>= 1)
#pragma unroll
      for (int i = 0; i < 4; i++) rsv[i] += __shfl_xor(rsv[i], m);
    if (cx == 0) {
#pragma unroll
      for (int i = 0; i < 4; i++) lsum[4 * ry + i] += rsv[i];
    }
    for (int ch = 0; ch < NCH; ch++) {
      __syncthreads();
#pragma unroll
      for (int i = 0; i < 16; i++) {
        const int idx = tid + i * 256;
        const int r = idx >> 5;
        const int c4 = (idx & 31) * 4;
        *(float4*)&Vs[r][c4] =
            *(const float4*)&sup[(size_t)(j0 + r) * DD + ch * CC + c4];
      }
      __syncthreads();
#pragma unroll 4
      for (int jp = 0; jp < JT; jp++) {
        const float4 p = *(const float4*)&Ps[jp][4 * ry];
        const float4 v = *(const float4*)&Vs[jp][4 * cx];
        const float pvv[4] = {p.x, p.y, p.z, p.w};
        const float vv[4] = {v.x, v.y, v.z, v.w};
#pragma unroll
        for (int i = 0; i < 4; i++)
#pragma unroll
          for (int j = 0; j < 4; j++)
            oacc[ch][i][j] += pvv[i] * vv[j];
      }
    }
  }
  __syncthreads();
  float linv[4];
#pragma unroll
  for (int i = 0; i < 4; i++) linv[i] = 1.f / lsum[4 * ry + i];
#pragma unroll
  for (int ch = 0; ch < NCH; ch++)
#pragma unroll
    for (int i = 0; i < 4; i++) {
      float4 o = {oacc[ch][i][0] * linv[i], oacc[ch][i][1] * linv[i],
                  oacc[ch][i][2] * linv[i], oacc[ch][i][3] * linv[i]};
      *(float4*)&out[(size_t)(i0 + 4 * ry + i) * DD + ch * CC + 4 * cx] = o;
    }
}

// ---------------------------------------------------------------------------
// Launch. ws layout (MFMA path, NEED = 152 MB + 32 KB):
//   P    : [0, 128MB)    bf16 [8192][8192]
//   xif  : [128,136MB)   e4m3 [8192][1024] (= fp8(16*xi))
//   supT : [136,152MB)   bf16 [1024][8192]
//   lsum : [152MB,+32KB) fp32 [8192]  (zeroed, filled by qk_fp8 atomics)
//   transients (consumed before P is written, alias the P region):
//     xb [0,16MB) bf16 [8192][1024];  tiT [16,18MB);  wT [18,20MB)
// NOTE: reference uses transferi for BOTH projections; transferj unused.
// ---------------------------------------------------------------------------
extern "C" void kernel_launch(void* const* d_in, const int* in_sizes, int n_in,
                              void* d_out, int out_size, void* d_ws, size_t ws_size,
                              hipStream_t stream) {
  const float* x  = (const float*)d_in[0];
  const float* wt = (const float*)d_in[1];
  const float* ti = (const float*)d_in[2];
  float* out = (float*)d_out;

  char* ws = (char*)d_ws;
  const size_t MB = 1024 * 1024;
  const size_t NEED = 152 * MB + NQ * sizeof(float);

  if (ws_size >= NEED) {
    unsigned short* P    = (unsigned short*)ws;
    unsigned char*  xif  = (unsigned char*)(ws + 128 * MB);
    unsigned short* supT = (unsigned short*)(ws + 136 * MB);
    float* lsum          = (float*)(ws + 152 * MB);
    unsigned short* xb   = (unsigned short*)ws;             // transient in P
    unsigned short* tiT  = (unsigned short*)(ws + 16 * MB); // transient in P
    unsigned short* wT   = (unsigned short*)(ws + 18 * MB); // transient in P

    const int n4 = NQ * DD / 4;
    f32_to_bf16<<<(n4 + 255) / 256, 256, 0, stream>>>(x, xb, n4);
    transpose_cvt<<<dim3(32, 32), 256, 0, stream>>>(ti, tiT, DD, DD);
    transpose_cvt<<<dim3(32, 32), 256, 0, stream>>>(wt, wT, DD, DD);
    zero_f32<<<NQ / 256, 256, 0, stream>>>(lsum, NQ);

    // xif[m][n] = e4m3(16 * sum_k xb[m][k]*ti[k][n])
    proj_gemm<DD, true><<<dim3(DD / 128, NQ / 128), 256, 0, stream>>>(xb, tiT, xif);
    // supT[n][m] = bf16(sum_k W[k][n]*x[m][k])
    proj_gemm<NQ, false><<<dim3(NQ / 128, DD / 128), 256, 0, stream>>>(wT, xb, supT);

    qk_fp8<<<dim3(NQ / 128, NQ / 128), 256, 0, stream>>>(xif, P, lsum);
    pv8<<<dim3(NQ / 256, DD / 128), 512, 0, stream>>>(P, supT, lsum, out);
  } else {
    float* xi32  = (float*)ws;
    float* sup32 = (float*)(ws + 32 * MB);
    dim3 ggrid(DD / BN, NQ / BM);
    gemm64<<<ggrid, 256, 0, stream>>>(x, ti, xi32, NQ, DD, DD);
    gemm64<<<ggrid, 256, 0, stream>>>(x, wt, sup32, NQ, DD, DD);
    fused_attn<<<NQ / IT, 256, 0, stream>>>(xi32, sup32, out);
  }
}

// Round 2
// 390.089 us; speedup vs baseline: 1.4241x; 1.4241x over previous
//
#include <hip/hip_runtime.h>
#include <hip/hip_bf16.h>
#include <cstddef>

// Problem constants (match reference).
#define NQ 8192
#define DD 1024

typedef __attribute__((ext_vector_type(8))) short s8v;     // 8 bf16 (4 VGPR)
typedef __attribute__((ext_vector_type(8))) int i8v;       // 32 fp8 bytes (8 VGPR)
typedef __attribute__((ext_vector_type(4))) float f32x4;   // 16x16 C/D frag
typedef __attribute__((ext_vector_type(16))) float f32x16; // 32x32 C/D frag

typedef const __attribute__((address_space(1))) unsigned int* gptr_t;
typedef __attribute__((address_space(3))) unsigned int* lptr_t;

#define SCALE_1_16 0x7B7B7B7Bu  // E8M0 123 = 2^-4 in every byte

__device__ inline unsigned short f2bf(float f) {
  union { float f; unsigned u; } v; v.f = f;
  unsigned r = (v.u + 0x7FFFu + ((v.u >> 16) & 1u)) >> 16;  // RNE
  return (unsigned short)r;
}
__device__ inline float bits2f(unsigned u) {
  union { unsigned u; float f; } v; v.u = u;
  return v.f;
}

// f32 -> OCP e4m3 bits, RNE, clamp to +-448.
__device__ inline unsigned char f2e4m3(float x) {
  union { float f; unsigned u; } v; v.f = x;
  const unsigned s = (v.u >> 31) << 7;
  unsigned au = v.u & 0x7FFFFFFFu;
  if (au > 0x43E00000u) au = 0x43E00000u;  // clamp |x| to 448.0
  if (au >= 0x3C800000u) {                 // |x| >= 2^-6: e4m3 normal
    const unsigned rounded = au + 0x7FFFFu + ((au >> 20) & 1u);  // RNE @ 3 mant
    const unsigned e8 = ((rounded >> 23) & 0xFF) - 120u;         // -127+7
    const unsigned m8 = (rounded >> 20) & 7u;
    return (unsigned char)(s | (e8 << 3) | m8);
  } else {                                 // subnormal
    union { unsigned u; float f; } a; a.u = au;
    const unsigned q = (unsigned)rintf(a.f * 512.0f);  // 0..8
    return (unsigned char)(s | q);
  }
}

// Register-only combine of two 16-B LDS loads into one fp8 MFMA operand.
__device__ inline i8v make_i8v(int4 a, int4 b) {
  i8v v;
  v[0] = a.x; v[1] = a.y; v[2] = a.z; v[3] = a.w;
  v[4] = b.x; v[5] = b.y; v[6] = b.z; v[7] = b.w;
  return v;
}

// ---------------------------------------------------------------------------
// m97-style bf16 MFMA main loop: C(128x128) += A(128xK) @ B(128xK)^T.
// BK=64, global_load_lds dwordx4 staging, 4 waves, each 64x64 via 4x4 of
// 16x16x32 bf16 MFMA. Used by proj_gemm and pv.
//
// LDS rows are 64 shorts = 128 B = exactly 32 banks, 16-B chunks
// XOR-swizzled by row&7 (global source column permuted; LDS dest linear per
// global_load_lds wave-uniform-base rule). Frag reads: chunk = (4s+lq)^(l16&7).
// Verified: 0 bank conflicts (round-0 counters).
// ---------------------------------------------------------------------------
template <int KDIM, int ASTR, int BSTR>
__device__ inline void mfma_core(const unsigned short* __restrict__ A,
                                 const unsigned short* __restrict__ B,
                                 int i0, int j0, int tid,
                                 unsigned short* AsU, unsigned short* BsU,
                                 f32x4 (&acc)[4][4]) {
  const int lane = tid & 63;
  const int w = tid >> 6;
  const int wr = (w >> 1) * 64;
  const int wc = (w & 1) * 64;
  const int l16 = lane & 15;
  const int lq = lane >> 4;
  const int srow = lane >> 3;                          // 0..7
  const int scol = (((lane & 7) ^ (srow & 7)) * 8);    // swizzled 16-B chunk

  for (int kk = 0; kk < KDIM; kk += 64) {
    __syncthreads();
#pragma unroll
    for (int t = 0; t < 4; t++) {
      const int r0 = w * 32 + t * 8;
      const unsigned short* g = &A[(size_t)(i0 + r0 + srow) * ASTR + kk + scol];
      __builtin_amdgcn_global_load_lds((gptr_t)(const void*)g,
                                       (lptr_t)(void*)&AsU[r0 * 64], 16, 0, 0);
    }
#pragma unroll
    for (int t = 0; t < 4; t++) {
      const int r0 = w * 32 + t * 8;
      const unsigned short* g = &B[(size_t)(j0 + r0 + srow) * BSTR + kk + scol];
      __builtin_amdgcn_global_load_lds((gptr_t)(const void*)g,
                                       (lptr_t)(void*)&BsU[r0 * 64], 16, 0, 0);
    }
    __syncthreads();

    const int h = l16 & 7;
    s8v af[4][2], bf[4][2];
#pragma unroll
    for (int t = 0; t < 4; t++)
#pragma unroll
      for (int s = 0; s < 2; s++) {
        const int ch = ((s * 4 + lq) ^ h) * 8;  // swizzled chunk offset
        af[t][s] = *(const s8v*)&AsU[(wr + 16 * t + l16) * 64 + ch];
        bf[t][s] = *(const s8v*)&BsU[(wc + 16 * t + l16) * 64 + ch];
      }
#pragma unroll
    for (int s = 0; s < 2; s++)
#pragma unroll
      for (int a = 0; a < 4; a++)
#pragma unroll
        for (int b = 0; b < 4; b++)
          acc[a][b] = __builtin_amdgcn_mfma_f32_16x16x32_bf16(
              af[a][s], bf[b][s], acc[a][b], 0, 0, 0);
  }
}

// ---------------------------------------------------------------------------
// fp32 -> bf16 elementwise.
// ---------------------------------------------------------------------------
__global__ void f32_to_bf16(const float* __restrict__ in,
                            unsigned short* __restrict__ out, int n4) {
  int i = (blockIdx.x * blockDim.x + threadIdx.x);
  if (i < n4) {
    const float4 v = *(const float4*)&in[i * 4];
    ushort4 o;
    o.x = f2bf(v.x); o.y = f2bf(v.y); o.z = f2bf(v.z); o.w = f2bf(v.w);
    *(ushort4*)&out[i * 4] = o;
  }
}

__global__ void zero_f32(float* __restrict__ p, int n) {
  const int i = blockIdx.x * blockDim.x + threadIdx.x;
  if (i < n) p[i] = 0.f;
}

__global__ void zero_f32v4(float* __restrict__ p, int n4) {
  const int i = blockIdx.x * blockDim.x + threadIdx.x;
  if (i < n4) *(float4*)&p[i * 4] = (float4){0.f, 0.f, 0.f, 0.f};
}

// ---------------------------------------------------------------------------
// fp32 [R][C] -> bf16 [C][R] transpose+convert (32x32 LDS tiles).
// ---------------------------------------------------------------------------
__global__ void transpose_cvt(const float* __restrict__ in,
                              unsigned short* __restrict__ out, int R, int C) {
  __shared__ float t[32][33];
  const int bx = blockIdx.x;
  const int by = blockIdx.y;
  const int x = threadIdx.x & 31;
  const int y = threadIdx.x >> 5;
#pragma unroll
  for (int i = 0; i < 32; i += 8)
    t[y + i][x] = in[(size_t)(by * 32 + y + i) * C + bx * 32 + x];
  __syncthreads();
#pragma unroll
  for (int i = 0; i < 32; i += 8)
    out[(size_t)(bx * 32 + y + i) * R + by * 32 + x] = f2bf(t[x][y + i]);
}

// ---------------------------------------------------------------------------
// Projection GEMM: C[m][n] = sum_k A[m][k] * BT[n][k], bf16 in, K=1024.
// FP8OUT=true writes e4m3(16*value) for the MX qk pass.
// ---------------------------------------------------------------------------
template <int NST, bool FP8OUT>
__global__ __launch_bounds__(256, 2)
void proj_gemm(const unsigned short* __restrict__ A,
               const unsigned short* __restrict__ BT,
               void* __restrict__ Cout) {
  __shared__ __align__(16) unsigned short As[128 * 64];
  __shared__ __align__(16) unsigned short Bs[128 * 64];
  const int tid = threadIdx.x;
  const int m0 = blockIdx.y * 128;
  const int n0 = blockIdx.x * 128;

  f32x4 acc[4][4];
#pragma unroll
  for (int a = 0; a < 4; a++)
#pragma unroll
    for (int b = 0; b < 4; b++) acc[a][b] = (f32x4){0.f, 0.f, 0.f, 0.f};

  mfma_core<DD, DD, DD>(A, BT, m0, n0, tid, As, Bs, acc);

  const int lane = tid & 63;
  const int w = tid >> 6;
  const int wr = (w >> 1) * 64, wc = (w & 1) * 64;
  const int l16 = lane & 15, lq = lane >> 4;
#pragma unroll
  for (int ti = 0; ti < 4; ti++)
#pragma unroll
    for (int r = 0; r < 4; r++) {
      const int row = m0 + wr + 16 * ti + lq * 4 + r;
#pragma unroll
      for (int tj = 0; tj < 4; tj++) {
        const int col = n0 + wc + 16 * tj + l16;
        if (FP8OUT) {
          ((unsigned char*)Cout)[(size_t)row * NST + col] =
              f2e4m3(acc[ti][tj][r] * 16.f);
        } else {
          ((unsigned short*)Cout)[(size_t)row * NST + col] = f2bf(acc[ti][tj][r]);
        }
      }
    }
}

// ---------------------------------------------------------------------------
// Pass 1: P = exp(xi @ xi^T) via MX-scaled fp8 MFMA (2x bf16 rate).
// xif holds e4m3(16*xi); both MFMA scales = 2^-4 undo the pre-scaling.
// 128x128 tile, 4 waves, each 64x64 = 2x2 of mfma_scale_f32_32x32x64_f8f6f4.
//
// Row-sum fusion v2 (round-1's 160-bpermute version cost 147us — reverted):
// each lane writes its 32 per-row partials (p0+p1) into padded LDS
// lsums[128][65] (conflict-free: bank = (row+col)%32, each (row,col) written
// by exactly one lane), one __syncthreads, then 128 threads sum 64 floats
// each and issue ONE atomicAdd per row.  ~600 cy/block (~2%), replaces the
// 22us row_sum kernel (128 MB P re-read).
// ---------------------------------------------------------------------------
__global__ __launch_bounds__(256, 3)
void qk_fp8(const unsigned char* __restrict__ xif,  // [8192][1024] e4m3
            unsigned short* __restrict__ P,         // [8192][8192] bf16 bits
            float* __restrict__ lsum) {             // [8192] fp32 (pre-zeroed)
  __shared__ __align__(16) unsigned char AsF[128 * 64];
  __shared__ __align__(16) unsigned char BsF[128 * 64];
  __shared__ float lsums[128][65];                  // 33.3 KB, padded stride
  const int tid = threadIdx.x;
  const int lane = tid & 63;
  const int w = tid >> 6;
  const int i0 = blockIdx.y * 128;
  const int j0 = blockIdx.x * 128;

  f32x16 acc[2][2];
#pragma unroll
  for (int a = 0; a < 2; a++)
#pragma unroll
    for (int b = 0; b < 2; b++)
#pragma unroll
      for (int r = 0; r < 16; r++) acc[a][b][r] = 0.f;

  const int srow = lane >> 2;  // 0..15: row within 16-row staging group
  const int slot = lane & 3;   // 16-B chunk slot within the row
  const int kb = lane >> 5;    // frag k-block (0/1)
  const int l31 = lane & 31;

  for (int kk = 0; kk < DD; kk += 64) {
    __syncthreads();
#pragma unroll
    for (int t = 0; t < 2; t++) {
      const int r = w * 32 + t * 16 + srow;
      const int c = slot ^ ((r >> 1) & 3);  // logical chunk for this slot
      const unsigned char* ga = &xif[(size_t)(i0 + r) * DD + kk + c * 16];
      const unsigned char* gb = &xif[(size_t)(j0 + r) * DD + kk + c * 16];
      __builtin_amdgcn_global_load_lds((gptr_t)(const void*)ga,
                                       (lptr_t)(void*)&AsF[(w * 32 + t * 16) * 64],
                                       16, 0, 0);
      __builtin_amdgcn_global_load_lds((gptr_t)(const void*)gb,
                                       (lptr_t)(void*)&BsF[(w * 32 + t * 16) * 64],
                                       16, 0, 0);
    }
    __syncthreads();

    i8v af[2], bf[2];
#pragma unroll
    for (int mi = 0; mi < 2; mi++) {
      const int ar = (w >> 1) * 64 + mi * 32 + l31;
      const int sw = (ar >> 1) & 3;
      const int4 q0 = *(const int4*)&AsF[ar * 64 + ((2 * kb + 0) ^ sw) * 16];
      const int4 q1 = *(const int4*)&AsF[ar * 64 + ((2 * kb + 1) ^ sw) * 16];
      af[mi] = make_i8v(q0, q1);
    }
#pragma unroll
    for (int nj = 0; nj < 2; nj++) {
      const int br = (w & 1) * 64 + nj * 32 + l31;
      const int sw = (br >> 1) & 3;
      const int4 q0 = *(const int4*)&BsF[br * 64 + ((2 * kb + 0) ^ sw) * 16];
      const int4 q1 = *(const int4*)&BsF[br * 64 + ((2 * kb + 1) ^ sw) * 16];
      bf[nj] = make_i8v(q0, q1);
    }
#pragma unroll
    for (int mi = 0; mi < 2; mi++)
#pragma unroll
      for (int nj = 0; nj < 2; nj++)
        acc[mi][nj] = __builtin_amdgcn_mfma_scale_f32_32x32x64_f8f6f4(
            af[mi], bf[nj], acc[mi][nj], 0 /*cbsz: fp8*/, 0 /*blgp: fp8*/,
            0, SCALE_1_16, 0, SCALE_1_16);
  }

  // Epilogue: p = exp(s) -> P (bf16) + LDS partial row sums.
  // 32x32 C layout: row = (reg&3) + 8*(reg>>2) + 4*(lane>>5), col = lane&31.
  const int mbase = (w >> 1) * 64;
  const int nbase = (w & 1) * 64;
  const int rowoff = 4 * (lane >> 5);
  const int cslot = (w & 1) * 32 + l31;  // column slot: wave n-half x lane
#pragma unroll
  for (int mi = 0; mi < 2; mi++)
#pragma unroll
    for (int r4 = 0; r4 < 4; r4++)
#pragma unroll
      for (int rr = 0; rr < 4; rr++) {
        const int reg = r4 * 4 + rr;
        const int rl = mbase + mi * 32 + rr + 8 * r4 + rowoff;
        const float p0 = __expf(acc[mi][0][reg]);
        const float p1 = __expf(acc[mi][1][reg]);
        const size_t base = (size_t)(i0 + rl) * NQ + j0 + nbase + l31;
        P[base]      = f2bf(p0);
        P[base + 32] = f2bf(p1);
        lsums[rl][cslot] = p0 + p1;  // each (rl,cslot) written exactly once
      }
  __syncthreads();
  if (tid < 128) {
    float s = 0.f;
#pragma unroll
    for (int c = 0; c < 64; c++) s += lsums[tid][c];
    atomicAdd(&lsum[i0 + tid], s);
  }
}

// ---------------------------------------------------------------------------
// Pass 2: out += (P @ supT^T) / lsum[row], K-split across blockIdx.z.
// Round-0 structure (m97 loop, proven 960 TF) with the occupancy lever:
// K-split 2 -> grid 64x8x2 = 1024 blocks = exactly 4/CU at
// __launch_bounds__(256,4).  VGPR check: 60 (round-0 count) + 64 acc = 124
// <= 128 budget; LDS 4x32 KB = 128 KB.  Partials atomicAdd'ed into
// pre-zeroed out with the 1/lsum scale applied per-partial (linear).
// ---------------------------------------------------------------------------
__global__ __launch_bounds__(256, 4)
void pv(const unsigned short* __restrict__ P,
        const unsigned short* __restrict__ supT,
        const float* __restrict__ lsum,
        float* __restrict__ out) {
  __shared__ __align__(16) unsigned short As[128 * 64];
  __shared__ __align__(16) unsigned short Bs[128 * 64];
  const int tid = threadIdx.x;
  const int i0 = blockIdx.x * 128;
  const int n0 = blockIdx.y * 128;
  const int k0 = blockIdx.z * (NQ / 2);

  f32x4 acc[4][4];
#pragma unroll
  for (int a = 0; a < 4; a++)
#pragma unroll
    for (int b = 0; b < 4; b++) acc[a][b] = (f32x4){0.f, 0.f, 0.f, 0.f};

  mfma_core<NQ / 2, NQ, NQ>(P + k0, supT + k0, i0, n0, tid, As, Bs, acc);

  const int lane = tid & 63;
  const int w = tid >> 6;
  const int wr = (w >> 1) * 64, wc = (w & 1) * 64;
  const int l16 = lane & 15, lq = lane >> 4;
#pragma unroll
  for (int ti = 0; ti < 4; ti++) {
#pragma unroll
    for (int r = 0; r < 4; r++) {
      const int row = i0 + wr + 16 * ti + lq * 4 + r;
      const float linv = 1.f / lsum[row];
#pragma unroll
      for (int tj = 0; tj < 4; tj++) {
        const int col = n0 + wc + 16 * tj + l16;
        atomicAdd(&out[(size_t)row * DD + col], acc[ti][tj][r] * linv);
      }
    }
  }
}

// ---------------------------------------------------------------------------
// Fallback fp32 path (round-1) — only if ws_size is too small.
// ---------------------------------------------------------------------------
#define BM 64
#define BN 64
#define BK 16

__global__ __launch_bounds__(256, 4)
void gemm64(const float* __restrict__ A, const float* __restrict__ B,
            float* __restrict__ C, int M, int N, int K) {
  __shared__ __align__(16) float As[BK][BM + 4];
  __shared__ __align__(16) float Bs[BK][BN + 4];
  const int tid = threadIdx.x;
  const int tx = tid & 15;
  const int ty = tid >> 4;
  const int row0 = blockIdx.y * BM;
  const int col0 = blockIdx.x * BN;
  float acc[4][4] = {};
  for (int k0 = 0; k0 < K; k0 += BK) {
    {
      const int r = tid >> 2;
      const int c4 = (tid & 3) * 4;
      const float4 v = *(const float4*)&A[(size_t)(row0 + r) * K + k0 + c4];
      As[c4 + 0][r] = v.x; As[c4 + 1][r] = v.y;
      As[c4 + 2][r] = v.z; As[c4 + 3][r] = v.w;
    }
    {
      const int r = tid >> 4;
      const int c4 = (tid & 15) * 4;
      *(float4*)&Bs[r][c4] = *(const float4*)&B[(size_t)(k0 + r) * N + col0 + c4];
    }
    __syncthreads();
#pragma unroll
    for (int k = 0; k < BK; k++) {
      const float4 a = *(const float4*)&As[k][4 * ty];
      const float4 b = *(const float4*)&Bs[k][4 * tx];
      const float av[4] = {a.x, a.y, a.z, a.w};
      const float bv[4] = {b.x, b.y, b.z, b.w};
#pragma unroll
      for (int i = 0; i < 4; i++)
#pragma unroll
        for (int j = 0; j < 4; j++)
          acc[i][j] += av[i] * bv[j];
    }
    __syncthreads();
  }
#pragma unroll
  for (int i = 0; i < 4; i++) {
    float4 o = {acc[i][0], acc[i][1], acc[i][2], acc[i][3]};
    *(float4*)&C[(size_t)(row0 + 4 * ty + i) * N + col0 + 4 * tx] = o;
  }
}

#define IT 32
#define JT 128
#define KC 32
#define CC 128
#define NCH (DD / CC)

__global__ __launch_bounds__(256, 1)
void fused_attn(const float* __restrict__ xi, const float* __restrict__ sup,
                float* __restrict__ out) {
  __shared__ __align__(16) float XiI[KC][IT + 4];
  __shared__ __align__(16) float XiJ[KC][JT + 4];
  __shared__ __align__(16) float Ps[JT][IT + 4];
  __shared__ __align__(16) float Vs[JT][CC + 4];
  __shared__ float lsum[IT];
  const int tid = threadIdx.x;
  const int i0 = blockIdx.x * IT;
  const int ry = tid >> 5;
  const int cx = tid & 31;
  if (tid < IT) lsum[tid] = 0.f;
  float oacc[NCH][4][4];
#pragma unroll
  for (int ch = 0; ch < NCH; ch++)
#pragma unroll
    for (int i = 0; i < 4; i++)
#pragma unroll
      for (int j = 0; j < 4; j++) oacc[ch][i][j] = 0.f;
  for (int j0 = 0; j0 < NQ; j0 += JT) {
    float sacc[4][4] = {};
    for (int kc = 0; kc < DD; kc += KC) {
      __syncthreads();
      {
        const int r = tid >> 3;
        const int k4 = (tid & 7) * 4;
        const float4 v = *(const float4*)&xi[(size_t)(i0 + r) * DD + kc + k4];
        XiI[k4 + 0][r] = v.x; XiI[k4 + 1][r] = v.y;
        XiI[k4 + 2][r] = v.z; XiI[k4 + 3][r] = v.w;
      }
#pragma unroll
      for (int i = 0; i < 4; i++) {
        const int idx = tid + i * 256;
        const int r = idx >> 3;
        const int k4 = (idx & 7) * 4;
        const float4 v = *(const float4*)&xi[(size_t)(j0 + r) * DD + kc + k4];
        XiJ[k4 + 0][r] = v.x; XiJ[k4 + 1][r] = v.y;
        XiJ[k4 + 2][r] = v.z; XiJ[k4 + 3][r] = v.w;
      }
      __syncthreads();
#pragma unroll
      for (int k = 0; k < KC; k++) {
        const float4 a = *(const float4*)&XiI[k][4 * ry];
        const float4 b = *(const float4*)&XiJ[k][4 * cx];
        const float av[4] = {a.x, a.y, a.z, a.w};
        const float bv[4] = {b.x, b.y, b.z, b.w};
#pragma unroll
        for (int i = 0; i < 4; i++)
#pragma unroll
          for (int j = 0; j < 4; j++)
            sacc[i][j] += av[i] * bv[j];
      }
    }
    __syncthreads();
    float rsv[4] = {0.f, 0.f, 0.f, 0.f};
#pragma unroll
    for (int i = 0; i < 4; i++)
#pragma unroll
      for (int j = 0; j < 4; j++) {
        const float p = __expf(sacc[i][j]);
        Ps[4 * cx + j][4 * ry + i] = p;
        rsv[i] += p;
      }
#pragma unroll
    for (int m = 16; m >= 1; m >>= 1)
#pragma unroll
      for (int i = 0; i < 4; i++) rsv[i] += __shfl_xor(rsv[i], m);
    if (cx == 0) {
#pragma unroll
      for (int i = 0; i < 4; i++) lsum[4 * ry + i] += rsv[i];
    }
    for (int ch = 0; ch < NCH; ch++) {
      __syncthreads();
#pragma unroll
      for (int i = 0; i < 16; i++) {
        const int idx = tid + i * 256;
        const int r = idx >> 5;
        const int c4 = (idx & 31) * 4;
        *(float4*)&Vs[r][c4] =
            *(const float4*)&sup[(size_t)(j0 + r) * DD + ch * CC + c4];
      }
      __syncthreads();
#pragma unroll 4
      for (int jp = 0; jp < JT; jp++) {
        const float4 p = *(const float4*)&Ps[jp][4 * ry];
        const float4 v = *(const float4*)&Vs[jp][4 * cx];
        const float pvv[4] = {p.x, p.y, p.z, p.w};
        const float vv[4] = {v.x, v.y, v.z, v.w};
#pragma unroll
        for (int i = 0; i < 4; i++)
#pragma unroll
          for (int j = 0; j < 4; j++)
            oacc[ch][i][j] += pvv[i] * vv[j];
      }
    }
  }
  __syncthreads();
  float linv[4];
#pragma unroll
  for (int i = 0; i < 4; i++) linv[i] = 1.f / lsum[4 * ry + i];
#pragma unroll
  for (int ch = 0; ch < NCH; ch++)
#pragma unroll
    for (int i = 0; i < 4; i++) {
      float4 o = {oacc[ch][i][0] * linv[i], oacc[ch][i][1] * linv[i],
                  oacc[ch][i][2] * linv[i], oacc[ch][i][3] * linv[i]};
      *(float4*)&out[(size_t)(i0 + 4 * ry + i) * DD + ch * CC + 4 * cx] = o;
    }
}

// ---------------------------------------------------------------------------
// Launch. ws layout (MFMA path, NEED = 152 MB + 32 KB):
//   P    : [0, 128MB)    bf16 [8192][8192]
//   xif  : [128,136MB)   e4m3 [8192][1024] (= fp8(16*xi))
//   supT : [136,152MB)   bf16 [1024][8192]
//   lsum : [152MB,+32KB) fp32 [8192]  (zeroed, filled by qk_fp8 atomics)
//   transients (consumed before P is written, alias the P region):
//     xb [0,16MB) bf16 [8192][1024];  tiT [16,18MB);  wT [18,20MB)
// NOTE: reference uses transferi for BOTH projections; transferj unused.
// ---------------------------------------------------------------------------
extern "C" void kernel_launch(void* const* d_in, const int* in_sizes, int n_in,
                              void* d_out, int out_size, void* d_ws, size_t ws_size,
                              hipStream_t stream) {
  const float* x  = (const float*)d_in[0];
  const float* wt = (const float*)d_in[1];
  const float* ti = (const float*)d_in[2];
  float* out = (float*)d_out;

  char* ws = (char*)d_ws;
  const size_t MB = 1024 * 1024;
  const size_t NEED = 152 * MB + NQ * sizeof(float);

  if (ws_size >= NEED) {
    unsigned short* P    = (unsigned short*)ws;
    unsigned char*  xif  = (unsigned char*)(ws + 128 * MB);
    unsigned short* supT = (unsigned short*)(ws + 136 * MB);
    float* lsum          = (float*)(ws + 152 * MB);
    unsigned short* xb   = (unsigned short*)ws;             // transient in P
    unsigned short* tiT  = (unsigned short*)(ws + 16 * MB); // transient in P
    unsigned short* wT   = (unsigned short*)(ws + 18 * MB); // transient in P

    const int n4 = NQ * DD / 4;
    zero_f32v4<<<(n4 + 255) / 256, 256, 0, stream>>>(out, n4);  // for pv atomics
    zero_f32<<<NQ / 256, 256, 0, stream>>>(lsum, NQ);
    f32_to_bf16<<<(n4 + 255) / 256, 256, 0, stream>>>(x, xb, n4);
    transpose_cvt<<<dim3(32, 32), 256, 0, stream>>>(ti, tiT, DD, DD);
    transpose_cvt<<<dim3(32, 32), 256, 0, stream>>>(wt, wT, DD, DD);

    // xif[m][n] = e4m3(16 * sum_k xb[m][k]*ti[k][n])
    proj_gemm<DD, true><<<dim3(DD / 128, NQ / 128), 256, 0, stream>>>(xb, tiT, xif);
    // supT[n][m] = bf16(sum_k W[k][n]*x[m][k])
    proj_gemm<NQ, false><<<dim3(NQ / 128, DD / 128), 256, 0, stream>>>(wT, xb, supT);

    qk_fp8<<<dim3(NQ / 128, NQ / 128), 256, 0, stream>>>(xif, P, lsum);
    pv<<<dim3(NQ / 128, DD / 128, 2), 256, 0, stream>>>(P, supT, lsum, out);
  } else {
    float* xi32  = (float*)ws;
    float* sup32 = (float*)(ws + 32 * MB);
    dim3 ggrid(DD / BN, NQ / BM);
    gemm64<<<ggrid, 256, 0, stream>>>(x, ti, xi32, NQ, DD, DD);
    gemm64<<<ggrid, 256, 0, stream>>>(x, wt, sup32, NQ, DD, DD);
    fused_attn<<<NQ / IT, 256, 0, stream>>>(xi32, sup32, out);
  }
}